// Round 7
// baseline (24.026 us; speedup 1.0000x reference)
//
#include <hip/hip_runtime.h>
#include <math.h>

#define NPTS 2048
#define KDIM 400
#define NBLK 256

typedef float f32x4 __attribute__((ext_vector_type(4)));

__device__ unsigned bar_g;   // .bss -> 0 at load; +NBLK per launch, stays aligned

// 16B device-coherent load (bypasses stale L1/L2, reads MALL).
__device__ __forceinline__ f32x4 load_coherent16(const void* p) {
    f32x4 r;
    asm volatile("global_load_dwordx4 %0, %1, off sc0 sc1"
                 : "=&v"(r) : "v"(p) : "memory");
    return r;
}

// Homogeneous fused kernel: every block does an FF slice (b = bid>>2, 100 of the
// 400 layer-3 cols) AND kval for 8 grid points, then ticket-barrier, then stages
// only the 128 integT columns its points touch, then computes 8 pts x 64 b outputs.
__global__ __launch_bounds__(512) void k_fused(
    const float* __restrict__ weights, const float* __restrict__ grid,
    const float* __restrict__ ff_w1, const float* __restrict__ ff_b1,
    const float* __restrict__ ff_w2, const float* __restrict__ ff_b2,
    const float* __restrict__ ff_w3, const float* __restrict__ ff_b3,
    const float* __restrict__ k_w1, const float* __restrict__ k_b1,
    const float* __restrict__ k_w2, const float* __restrict__ k_b2,
    const float* __restrict__ k_w3, const float* __restrict__ k_b3,
    float* __restrict__ integT,      // [400][64] transposed
    float2* __restrict__ out)
{
    __shared__ __align__(16) float S[12160];   // 48.6 KB
    // FF scratch:
    float* wrow = S;          // 256
    float* h1   = S + 256;    // 120
    float* h2   = S + 376;    // 240
    float* p1   = S + 616;    // 4*120
    float* p2   = S + 1096;   // 2*240
    float* p3   = S + 1576;   // 4*100
    // kval region (disjoint):
    float* sw1  = S + 1976;   // 80
    float* sb1  = S + 2056;   // 40
    float* sw2  = S + 2096;   // 800
    float* sb2  = S + 2896;   // 40
    float* sw3  = S + 2936;   // 40
    float* sb3  = S + 2976;   // 2
    float* kpart= S + 2980;   // 512
    float* kvs  = S + 3492;   // [2][16][8]
    int* kidxs  = (int*)(S + 3748); // [16][8]
    float* Lcol = S + 3904;   // [128][64] staged integT columns (16B-aligned)

    const int t   = threadIdx.x;
    const int bid = blockIdx.x;
    const int b   = bid >> 2;          // batch row this block produces
    const int qc  = (bid & 3) * 100;   // layer-3 column slice

    // ---- load kval weights + weights row up front ----
    for (int i = t; i < 80;  i += 512) sw1[i] = k_w1[i];
    for (int i = t; i < 800; i += 512) sw2[i] = k_w2[i];
    if (t < 40) { sb1[t] = k_b1[t]; sb2[t] = k_b2[t]; sw3[t] = k_w3[t]; }
    if (t < 2)  sb3[t] = k_b3[t];
    if (t < 256) wrow[t] = weights[b * 256 + t];
    __syncthreads();

    // ---- FF layer 1: 120 outs, 4-way split-K (64 each) ----
    if (t < 480) {
        const int seg = t / 120, o = t - seg * 120;
        float s = (seg == 0) ? ff_b1[o] : 0.f;
        const int i0 = seg * 64;
        #pragma unroll 16
        for (int i = 0; i < 64; ++i)
            s = fmaf(wrow[i0 + i], ff_w1[(i0 + i) * 120 + o], s);
        p1[seg * 120 + o] = s;
    }
    __syncthreads();
    if (t < 120) h1[t] = tanhf(p1[t] + p1[120 + t] + p1[240 + t] + p1[360 + t]);
    __syncthreads();

    // ---- FF layer 2: 240 outs, 2-way split-K (60 each) ----
    if (t < 480) {
        const int seg = t / 240, o = t - seg * 240;
        float s = (seg == 0) ? ff_b2[o] : 0.f;
        const int i0 = seg * 60;
        #pragma unroll 15
        for (int i = 0; i < 60; ++i)
            s = fmaf(h1[i0 + i], ff_w2[(i0 + i) * 240 + o], s);
        p2[seg * 240 + o] = s;
    }
    __syncthreads();
    if (t < 240) h2[t] = tanhf(p2[t] + p2[240 + t]);
    __syncthreads();

    // ---- FF layer 3: 100 cols, 4-way split-K over 240 (60 each) ----
    if (t < 400) {
        const int seg = t / 100, o = t - seg * 100, oc = qc + o;
        float s = (seg == 0) ? ff_b3[oc] : 0.f;
        const int i0 = seg * 60;
        #pragma unroll 15
        for (int i = 0; i < 60; ++i)
            s = fmaf(h2[i0 + i], ff_w3[(i0 + i) * 400 + oc], s);
        p3[seg * 100 + o] = s;
    }
    __syncthreads();
    if (t < 100)                       // transposed agent-coherent store
        __hip_atomic_store(&integT[(qc + t) * 64 + b],
                           p3[t] + p3[100 + t] + p3[200 + t] + p3[300 + t],
                           __ATOMIC_RELAXED, __HIP_MEMORY_SCOPE_AGENT);

    // ---- kval: 8 points x 16 slots x 2 fields x 2 g-halves = 512 tasks ----
    {
        const int q    = t >> 1;       // (f, slot, pt)
        const int gh   = t & 1;        // g half
        const int f    = q >> 7;
        const int slot = (q >> 3) & 15;
        const int pt   = q & 7;
        const int n    = bid * 8 + pt;
        const float2 g2 = ((const float2*)grid)[n];
        const float x = g2.x, y = g2.y;
        const int ilx = (int)ceilf((x - 0.15f) * 20.0f - 0.01f);
        const int ily = (int)ceilf((y - 0.15f) * 20.0f - 0.01f);
        const int ix = ilx + (slot >> 2);
        const int iy = ily + (slot & 3);

        float part = 0.f;
        int k = 0;
        if (ix >= 0 && ix < 20 && iy >= 0 && iy < 20) {
            // replicate reference f32 arithmetic exactly (no fp-contract)
            const float gx = __fmul_rn((float)ix, 0.05f);
            const float gy = __fmul_rn((float)iy, 0.05f);
            const float lx = __fsub_rn(x, gx);
            const float ly = __fsub_rn(y, gy);
            if (lx >= 0.f && lx <= 0.15f && ly >= 0.f && ly <= 0.15f) {
                k = ix * 20 + iy;
                float hv[20];
                #pragma unroll
                for (int hh = 0; hh < 20; ++hh)
                    hv[hh] = fmaxf(0.f,
                        fmaf(lx, sw1[f * 40 + hh],
                        fmaf(ly, sw1[f * 40 + 20 + hh], sb1[f * 20 + hh])));
                part = (gh == 0) ? sb3[f] : 0.f;
                const int g0 = gh * 10;
                #pragma unroll
                for (int gg = 0; gg < 10; ++gg) {
                    const int g = g0 + gg;
                    float s = sb2[f * 20 + g];
                    #pragma unroll
                    for (int hh = 0; hh < 20; ++hh)
                        s = fmaf(hv[hh], sw2[f * 400 + hh * 20 + g], s);
                    part = fmaf(fmaxf(0.f, s), sw3[f * 20 + g], part);
                }
            }
        }
        kpart[t] = part;
        __syncthreads();
        if (gh == 0) {
            kvs[f * 128 + slot * 8 + pt] = part + kpart[t + 1];
            if (f == 0) kidxs[slot * 8 + pt] = k;   // k=0 with kv=0 is harmless
        }
    }
    __syncthreads();

    // ---- init-free monotonic ticket barrier (no fences, no memset) ----
    if (t == 0) {
        const unsigned r = __hip_atomic_fetch_add(&bar_g, 1u, __ATOMIC_RELAXED,
                                                  __HIP_MEMORY_SCOPE_AGENT);
        const unsigned target = (r & ~(unsigned)(NBLK - 1)) + (unsigned)NBLK;
        while ((int)(__hip_atomic_load(&bar_g, __ATOMIC_RELAXED,
                                       __HIP_MEMORY_SCOPE_AGENT) - target) < 0)
            __builtin_amdgcn_s_sleep(1);
    }
    __syncthreads();

    // ---- stage the 128 needed integT columns: 4 coherent f32x4 per thread ----
    {
        f32x4 tmp[4];
        #pragma unroll
        for (int r = 0; r < 4; ++r) {
            const int c = (t >> 4) + r * 32;           // column slot 0..127
            const int kcol = kidxs[c];
            tmp[r] = load_coherent16(
                (const void*)(integT + kcol * 64 + (t & 15) * 4));
        }
        asm volatile("s_waitcnt vmcnt(0)" ::: "memory");
        __builtin_amdgcn_sched_barrier(0);
        #pragma unroll
        for (int r = 0; r < 4; ++r) {
            const int c = (t >> 4) + r * 32;
            ((f32x4*)Lcol)[c * 16 + (t & 15)] = tmp[r];
        }
    }
    __syncthreads();

    // ---- phase 2: thread = (pt, b); 16 LDS gathers x 2 fields ----
    {
        const int pt = t >> 6;         // 0..7
        const int bb = t & 63;         // 0..63
        float a0 = 0.f, a1 = 0.f;
        #pragma unroll
        for (int j = 0; j < 16; ++j) {
            const float w = Lcol[(j * 8 + pt) * 64 + bb];
            a0 = fmaf(kvs[j * 8 + pt], w, a0);
            a1 = fmaf(kvs[128 + j * 8 + pt], w, a1);
        }
        out[bb * NPTS + bid * 8 + pt] =
            make_float2(1.f / (1.f + __expf(-a0)), 1.f / (1.f + __expf(-a1)));
    }
}

extern "C" void kernel_launch(void* const* d_in, const int* in_sizes, int n_in,
                              void* d_out, int out_size, void* d_ws, size_t ws_size,
                              hipStream_t stream) {
    const float* weights = (const float*)d_in[0];
    const float* grid    = (const float*)d_in[1];
    const float* ff_w1   = (const float*)d_in[2];
    const float* ff_b1   = (const float*)d_in[3];
    const float* ff_w2   = (const float*)d_in[4];
    const float* ff_b2   = (const float*)d_in[5];
    const float* ff_w3   = (const float*)d_in[6];
    const float* ff_b3   = (const float*)d_in[7];
    const float* k_w1    = (const float*)d_in[8];
    const float* k_b1    = (const float*)d_in[9];
    const float* k_w2    = (const float*)d_in[10];
    const float* k_b2    = (const float*)d_in[11];
    const float* k_w3    = (const float*)d_in[12];
    const float* k_b3    = (const float*)d_in[13];

    float* integT = (float*)d_ws;      // [400][64] floats

    k_fused<<<NBLK, 512, 0, stream>>>(
        weights, grid, ff_w1, ff_b1, ff_w2, ff_b2, ff_w3, ff_b3,
        k_w1, k_b1, k_w2, k_b2, k_w3, k_b3,
        integT, (float2*)d_out);
}

// Round 8
// 15.095 us; speedup vs baseline: 1.5917x; 1.5917x over previous
//
#include <hip/hip_runtime.h>
#include <math.h>

#define NPTS 2048
#define KDIM 400

// Kernel 1: blocks 0..127 = FF (2 per batch row, split-K); blocks 128..255 =
// kval, 16 points/block, thread = (f, slot, pt) -> ~420 serial FMA per thread.
__global__ __launch_bounds__(512) void k_ff_and_kval(
    const float* __restrict__ weights, const float* __restrict__ grid,
    const float* __restrict__ ff_w1, const float* __restrict__ ff_b1,
    const float* __restrict__ ff_w2, const float* __restrict__ ff_b2,
    const float* __restrict__ ff_w3, const float* __restrict__ ff_b3,
    const float* __restrict__ k_w1, const float* __restrict__ k_b1,
    const float* __restrict__ k_w2, const float* __restrict__ k_b2,
    const float* __restrict__ k_w3, const float* __restrict__ k_b3,
    float* __restrict__ integ, float* __restrict__ kv0,
    float* __restrict__ kv1, int* __restrict__ kidx)
{
    const int t = threadIdx.x;
    if (blockIdx.x < 128) {
        // ---- FeedForward: block pair (b, half), split-K layers (proven R2) ----
        const int b = blockIdx.x >> 1, half = blockIdx.x & 1;
        __shared__ float wrow[256], h1[120], h2[240];
        __shared__ float p1[4][120], p2[2][240], p3[2][200];

        if (t < 256) wrow[t] = weights[b * 256 + t];
        __syncthreads();

        if (t < 480) {           // layer 1: 120 outs, 4-way split-K (64 each)
            const int seg = t / 120, o = t - seg * 120;
            float s = (seg == 0) ? ff_b1[o] : 0.f;
            const int i0 = seg * 64;
            #pragma unroll 16
            for (int i = 0; i < 64; ++i)
                s = fmaf(wrow[i0 + i], ff_w1[(i0 + i) * 120 + o], s);
            p1[seg][o] = s;
        }
        __syncthreads();
        if (t < 120) h1[t] = tanhf(p1[0][t] + p1[1][t] + p1[2][t] + p1[3][t]);
        __syncthreads();

        if (t < 480) {           // layer 2: 240 outs, 2-way split-K (60 each)
            const int seg = t / 240, o = t - seg * 240;
            float s = (seg == 0) ? ff_b2[o] : 0.f;
            const int i0 = seg * 60;
            #pragma unroll 15
            for (int i = 0; i < 60; ++i)
                s = fmaf(h1[i0 + i], ff_w2[(i0 + i) * 240 + o], s);
            p2[seg][o] = s;
        }
        __syncthreads();
        if (t < 240) h2[t] = tanhf(p2[0][t] + p2[1][t]);
        __syncthreads();

        if (t < 400) {           // layer 3: this block's 200 outs, 2-way split-K
            const int seg = t / 200, o = t - seg * 200, oc = half * 200 + o;
            float s = (seg == 0) ? ff_b3[oc] : 0.f;
            const int i0 = seg * 120;
            #pragma unroll 15
            for (int i = 0; i < 120; ++i)
                s = fmaf(h2[i0 + i], ff_w3[(i0 + i) * 400 + oc], s);
            p3[seg][o] = s;
        }
        __syncthreads();
        if (t < 200) integ[b * 400 + half * 200 + t] = p3[0][t] + p3[1][t];
    } else {
        // ---- kval: 16 points, thread = (f, slot, pt); f-split halves chain ----
        __shared__ float sw1[80], sb1[40], sw2[800], sb2[40], sw3[40], sb3[2];
        for (int i = t; i < 80;  i += 512) sw1[i] = k_w1[i];
        for (int i = t; i < 800; i += 512) sw2[i] = k_w2[i];
        if (t < 40) { sb1[t] = k_b1[t]; sb2[t] = k_b2[t]; sw3[t] = k_w3[t]; }
        if (t < 2)  sb3[t] = k_b3[t];
        __syncthreads();

        const int pid  = blockIdx.x - 128;   // 0..127, 16 points each
        const int f    = t >> 8;             // 0/1
        const int idx  = t & 255;
        const int slot = idx >> 4;           // 0..15 -> 4x4 window
        const int pt   = idx & 15;
        const int n    = pid * 16 + pt;
        const float2 g2 = ((const float2*)grid)[n];
        const float x = g2.x, y = g2.y;
        const int ilx = (int)ceilf((x - 0.15f) * 20.0f - 0.01f);
        const int ily = (int)ceilf((y - 0.15f) * 20.0f - 0.01f);
        const int ix = ilx + (slot >> 2);
        const int iy = ily + (slot & 3);

        float kv = 0.f;
        int k = 0;
        if (ix >= 0 && ix < 20 && iy >= 0 && iy < 20) {
            // replicate reference f32 arithmetic exactly (no fp-contract)
            const float gx = __fmul_rn((float)ix, 0.05f);
            const float gy = __fmul_rn((float)iy, 0.05f);
            const float lx = __fsub_rn(x, gx);
            const float ly = __fsub_rn(y, gy);
            if (lx >= 0.f && lx <= 0.15f && ly >= 0.f && ly <= 0.15f) {
                k = ix * 20 + iy;
                float hv[20];
                #pragma unroll
                for (int hh = 0; hh < 20; ++hh)
                    hv[hh] = fmaxf(0.f,
                        fmaf(lx, sw1[f * 40 + hh],
                        fmaf(ly, sw1[f * 40 + 20 + hh], sb1[f * 20 + hh])));
                float o = sb3[f];
                #pragma unroll
                for (int g = 0; g < 20; ++g) {
                    float s = sb2[f * 20 + g];
                    #pragma unroll
                    for (int hh = 0; hh < 20; ++hh)
                        s = fmaf(hv[hh], sw2[f * 400 + hh * 20 + g], s);
                    o = fmaf(fmaxf(0.f, s), sw3[f * 20 + g], o);
                }
                kv = o;
            }
        }
        (f ? kv1 : kv0)[slot * NPTS + n] = kv;
        if (f == 0) kidx[slot * NPTS + n] = k;   // k=0 with kv=0 is harmless
    }
}

// Kernel 2: block = (b, n-quarter); integ row staged in LDS; 1 thread/(b,n).
__global__ __launch_bounds__(512) void k_field(
    const float* __restrict__ integ, const float* __restrict__ kv0,
    const float* __restrict__ kv1, const int* __restrict__ kidx,
    float2* __restrict__ out)
{
    __shared__ float Li[KDIM];
    const int b  = blockIdx.x >> 2;
    const int n  = (blockIdx.x & 3) * 512 + threadIdx.x;
    if (threadIdx.x < KDIM) Li[threadIdx.x] = integ[b * KDIM + threadIdx.x];
    __syncthreads();

    float a0 = 0.f, a1 = 0.f;
    #pragma unroll
    for (int j = 0; j < 16; ++j) {
        const float w = Li[kidx[j * NPTS + n]];
        a0 = fmaf(kv0[j * NPTS + n], w, a0);
        a1 = fmaf(kv1[j * NPTS + n], w, a1);
    }
    out[b * NPTS + n] = make_float2(1.f / (1.f + __expf(-a0)),
                                    1.f / (1.f + __expf(-a1)));
}

extern "C" void kernel_launch(void* const* d_in, const int* in_sizes, int n_in,
                              void* d_out, int out_size, void* d_ws, size_t ws_size,
                              hipStream_t stream) {
    const float* weights = (const float*)d_in[0];
    const float* grid    = (const float*)d_in[1];
    const float* ff_w1   = (const float*)d_in[2];
    const float* ff_b1   = (const float*)d_in[3];
    const float* ff_w2   = (const float*)d_in[4];
    const float* ff_b2   = (const float*)d_in[5];
    const float* ff_w3   = (const float*)d_in[6];
    const float* ff_b3   = (const float*)d_in[7];
    const float* k_w1    = (const float*)d_in[8];
    const float* k_b1    = (const float*)d_in[9];
    const float* k_w2    = (const float*)d_in[10];
    const float* k_b2    = (const float*)d_in[11];
    const float* k_w3    = (const float*)d_in[12];
    const float* k_b3    = (const float*)d_in[13];

    float* integ = (float*)d_ws;                 // 64*400
    float* kv0   = integ + 64 * KDIM;            // 16*2048
    float* kv1   = kv0 + 16 * NPTS;              // 16*2048
    int*   kidx  = (int*)(kv1 + 16 * NPTS);      // 16*2048

    k_ff_and_kval<<<256, 512, 0, stream>>>(
        weights, grid, ff_w1, ff_b1, ff_w2, ff_b2, ff_w3, ff_b3,
        k_w1, k_b1, k_w2, k_b2, k_w3, k_b3,
        integ, kv0, kv1, kidx);

    k_field<<<256, 512, 0, stream>>>(
        integ, kv0, kv1, kidx, (float2*)d_out);
}